// Round 2
// baseline (394.144 us; speedup 1.0000x reference)
//
#include <hip/hip_runtime.h>
#include <hip/hip_bf16.h>
#include <stdint.h>

#define B_ 16
#define N_ 16384
#define D_ 128
#define E_ 65536

typedef __attribute__((ext_vector_type(8))) __bf16 bf16x8;
typedef __attribute__((ext_vector_type(4))) float f32x4;

__device__ __forceinline__ uint16_t f2bf(float f) {
    union { float f; uint32_t u; } v;
    v.f = f;
    uint32_t u = v.u;
    uint32_t r = (u + 0x7fffu + ((u >> 16) & 1u)) >> 16;
    return (uint16_t)r;
}

// ---- edge_index layout probe: int64 (odd words zero) vs int32 ----
__global__ void k_detect(const int* __restrict__ ei, int* __restrict__ flag) {
    __shared__ int nz;
    if (threadIdx.x == 0) nz = 0;
    __syncthreads();
    if (ei[2 * threadIdx.x + 1] != 0) atomicAdd(&nz, 1);
    __syncthreads();
    if (threadIdx.x == 0) *flag = (nz == 0) ? 1 : 0;
}

// ---- CSR build kernels (edges shared across all 16 graphs) ----

__global__ void k_count(const int* __restrict__ ei, const int* __restrict__ flag,
                        int* __restrict__ deg) {
    int e = blockIdx.x * 256 + threadIdx.x;
    int f = *flag;
    int d = f ? ei[2 * (E_ + e)] : ei[E_ + e];   // dst
    atomicAdd(&deg[d], 1);
}

__global__ void k_scan(const int* __restrict__ deg, int* __restrict__ off,
                       int* __restrict__ cur) {
    __shared__ int part[256];
    __shared__ int pre[257];
    int t = threadIdx.x;
    int base = t * 64;                // 16384 / 256
    int s = 0;
    for (int i = 0; i < 64; i++) s += deg[base + i];
    part[t] = s;
    __syncthreads();
    if (t == 0) {
        int run = 0;
        for (int i = 0; i < 256; i++) { pre[i] = run; run += part[i]; }
        pre[256] = run;
    }
    __syncthreads();
    int run = pre[t];
    for (int i = 0; i < 64; i++) {
        off[base + i] = run;
        cur[base + i] = run;
        run += deg[base + i];
    }
    if (t == 0) off[N_] = pre[256];
}

__global__ void k_fill(const int* __restrict__ ei, const int* __restrict__ flag,
                       int* __restrict__ cur, int* __restrict__ adj) {
    int e = blockIdx.x * 256 + threadIdx.x;
    int f = *flag;
    int s = f ? ei[2 * e] : ei[e];               // src
    int d = f ? ei[2 * (E_ + e)] : ei[E_ + e];   // dst
    int p = atomicAdd(&cur[d], 1);
    adj[p] = s;
}

// ---- weight prepack (fp32 -> bf16) into B-fragment order ----
// B-frag: lane holds B[k = ks*32 + (lane>>4)*8 + j][n = nt*16 + (lane&15)], j=0..7
// B[k][n] = k<128 ? W_self[n][k] : W_neigh[n][k-128]
__global__ void k_pack(const float* __restrict__ wself,
                       const float* __restrict__ wneigh,
                       uint16_t* __restrict__ wpack) {
    int g = blockIdx.x * 256 + threadIdx.x;  // 0..32767
    int j = g & 7;
    int lane = (g >> 3) & 63;
    int nt = (g >> 9) & 7;
    int ks = g >> 12;
    int k = ks * 32 + (lane >> 4) * 8 + j;
    int n = nt * 16 + (lane & 15);
    float v = (k < 128) ? wself[n * 128 + k] : wneigh[n * 128 + (k - 128)];
    wpack[g] = f2bf(v);
}

// ---- fused main kernel: stage x|neigh tile -> MFMA GEMM -> LN -> ReLU ----

__global__ __launch_bounds__(256) void k_main(
    const float* __restrict__ x,         // fp32 [16][16384][128]
    const int* __restrict__ off,         // [N+1]
    const int* __restrict__ adj,         // [E]
    const uint16_t* __restrict__ wpack,  // [8][8][64][8] bf16 frags
    const float* __restrict__ bias,
    const float* __restrict__ gamma_,
    const float* __restrict__ beta_,
    float* __restrict__ out) {
    // A-tile (frag order, 32768 B) aliased with C-tile (fp32, 33792 B)
    __shared__ __align__(16) unsigned char smem[33792];
    __shared__ float prm[3][128];
    uint16_t* As = (uint16_t*)smem;
    float* Cs = (float*)smem;

    int t = threadIdx.x;
    int b = blockIdx.x & 15;     // graph id fastest -> graph->XCD affinity
    int tile = blockIdx.x >> 4;  // 0..255
    int node0 = tile * 64;

    if (t < 128) {
        prm[0][t] = bias[t];
        prm[1][t] = gamma_[t];
        prm[2][t] = beta_[t];
    }

    int r = t >> 2;   // row in tile 0..63
    int q = t & 3;    // 32-dim quarter 0..3
    int node = node0 + r;
    const size_t xrow_base = ((size_t)b * N_ + node) * D_;
    int mt = r >> 4, m = r & 15;

    // --- stage x rows (k = 0..127) into frag-order LDS, fp32 -> bf16 ---
    {
        const float4* xv = (const float4*)(x + xrow_base);
#pragma unroll
        for (int c = 0; c < 4; c++) {   // 8-element chunks
            float4 a0 = xv[q * 8 + 2 * c + 0];
            float4 a1 = xv[q * 8 + 2 * c + 1];
            float f[8] = {a0.x, a0.y, a0.z, a0.w, a1.x, a1.y, a1.z, a1.w};
            uint32_t pk[4];
#pragma unroll
            for (int p = 0; p < 4; p++)
                pk[p] = (uint32_t)f2bf(f[2 * p]) | ((uint32_t)f2bf(f[2 * p + 1]) << 16);
            int kc = q * 4 + c;  // chunk index 0..15
            int ks = kc >> 2, qd = kc & 3;
            uint4 v = make_uint4(pk[0], pk[1], pk[2], pk[3]);
            *(uint4*)&As[(((ks * 4 + mt) * 64) + qd * 16 + m) * 8] = v;
        }
    }

    // --- gather neighbor mean (k = 128..255) in fp32 ---
    {
        int o0 = off[node], o1 = off[node + 1];
        float acc[32];
#pragma unroll
        for (int i = 0; i < 32; i++) acc[i] = 0.f;
        for (int e = o0; e < o1; e++) {
            int nbr = adj[e];
            const float4* nv = (const float4*)(x + ((size_t)b * N_ + nbr) * D_);
#pragma unroll
            for (int cc = 0; cc < 8; cc++) {
                float4 v = nv[q * 8 + cc];
                acc[cc * 4 + 0] += v.x;
                acc[cc * 4 + 1] += v.y;
                acc[cc * 4 + 2] += v.z;
                acc[cc * 4 + 3] += v.w;
            }
        }
        float scale = 1.f / fmaxf((float)(o1 - o0), 1.f);
#pragma unroll
        for (int c = 0; c < 4; c++) {
            uint32_t pk[4];
#pragma unroll
            for (int p = 0; p < 4; p++) {
                uint16_t lo = f2bf(acc[c * 8 + 2 * p + 0] * scale);
                uint16_t hi = f2bf(acc[c * 8 + 2 * p + 1] * scale);
                pk[p] = (uint32_t)lo | ((uint32_t)hi << 16);
            }
            int kc = 16 + q * 4 + c;  // chunks 16..31
            int ks = kc >> 2, qd = kc & 3;
            uint4 v = make_uint4(pk[0], pk[1], pk[2], pk[3]);
            *(uint4*)&As[(((ks * 4 + mt) * 64) + qd * 16 + m) * 8] = v;
        }
    }

    __syncthreads();

    // --- MFMA K-loop: each wave owns 2 n-tiles (32 output cols), all 64 rows ---
    int wv = t >> 6;
    int lane = t & 63;
    f32x4 accv[4][2];
#pragma unroll
    for (int i = 0; i < 4; i++)
#pragma unroll
        for (int j = 0; j < 2; j++) {
            f32x4 z = {0.f, 0.f, 0.f, 0.f};
            accv[i][j] = z;
        }

    const uint4* wp = (const uint4*)wpack;
#pragma unroll
    for (int ks = 0; ks < 8; ks++) {
        uint4 b0u = wp[(ks * 8 + 2 * wv + 0) * 64 + lane];
        uint4 b1u = wp[(ks * 8 + 2 * wv + 1) * 64 + lane];
        bf16x8 bf0 = __builtin_bit_cast(bf16x8, b0u);
        bf16x8 bf1 = __builtin_bit_cast(bf16x8, b1u);
#pragma unroll
        for (int mtt = 0; mtt < 4; mtt++) {
            bf16x8 a = *(const bf16x8*)&As[((ks * 4 + mtt) * 64 + lane) * 8];
            accv[mtt][0] = __builtin_amdgcn_mfma_f32_16x16x32_bf16(a, bf0, accv[mtt][0], 0, 0, 0);
            accv[mtt][1] = __builtin_amdgcn_mfma_f32_16x16x32_bf16(a, bf1, accv[mtt][1], 0, 0, 0);
        }
    }

    __syncthreads();  // As is dead; reuse as Cs

    // C/D layout: row = (lane>>4)*4 + reg (+mt*16), col = lane&15 (+ntile*16)
    // Cs layout: addr = row*132 + (col>>5)*33 + (col&31)
#pragma unroll
    for (int mtt = 0; mtt < 4; mtt++)
#pragma unroll
        for (int ntl = 0; ntl < 2; ntl++)
#pragma unroll
            for (int rg = 0; rg < 4; rg++) {
                int row = mtt * 16 + (lane >> 4) * 4 + rg;
                int col = (2 * wv + ntl) * 16 + (lane & 15);
                Cs[row * 132 + (col >> 5) * 33 + (col & 31)] = accv[mtt][ntl][rg];
            }

    __syncthreads();

    // --- bias + LayerNorm + ReLU + fp32 store ---
    {
        float s1 = 0.f, s2 = 0.f;
#pragma unroll
        for (int i = 0; i < 32; i++) {
            float v = Cs[r * 132 + q * 33 + i] + prm[0][q * 32 + i];
            s1 += v;
            s2 += v * v;
        }
        s1 += __shfl_xor(s1, 1, 64);
        s2 += __shfl_xor(s2, 1, 64);
        s1 += __shfl_xor(s1, 2, 64);
        s2 += __shfl_xor(s2, 2, 64);
        float mu = s1 * (1.f / 128.f);
        float var = s2 * (1.f / 128.f) - mu * mu;
        float rstd = rsqrtf(var + 1e-5f);

        float* orow = out + xrow_base;
#pragma unroll
        for (int c = 0; c < 8; c++) {   // 4-float groups
            float4 o;
            float tmp[4];
#pragma unroll
            for (int j = 0; j < 4; j++) {
                int i0 = c * 4 + j;
                int d0 = q * 32 + i0;
                float v = Cs[r * 132 + q * 33 + i0] + prm[0][d0];
                tmp[j] = fmaxf((v - mu) * rstd * prm[1][d0] + prm[2][d0], 0.f);
            }
            o.x = tmp[0]; o.y = tmp[1]; o.z = tmp[2]; o.w = tmp[3];
            *(float4*)&orow[q * 32 + c * 4] = o;
        }
    }
}

extern "C" void kernel_launch(void* const* d_in, const int* in_sizes, int n_in,
                              void* d_out, int out_size, void* d_ws, size_t ws_size,
                              hipStream_t stream) {
    (void)in_sizes; (void)n_in; (void)out_size; (void)ws_size;
    const float* x      = (const float*)d_in[0];
    const int*   ei     = (const int*)d_in[1];
    // d_in[2] = batch_size (16), compile-time constant here
    const float* wself  = (const float*)d_in[3];
    const float* wneigh = (const float*)d_in[4];
    const float* bias   = (const float*)d_in[5];
    const float* gma    = (const float*)d_in[6];
    const float* bta    = (const float*)d_in[7];
    float* out = (float*)d_out;

    char* ws = (char*)d_ws;
    int* deg        = (int*)(ws);                 // 16384 ints   @0
    int* off        = (int*)(ws + 65536);         // 16385 ints   @65536
    int* cur        = (int*)(ws + 131584);        // 16384 ints   @131584
    int* adj        = (int*)(ws + 197120);        // 65536 ints   @197120
    uint16_t* wpack = (uint16_t*)(ws + 459264);   // 32768 bf16   @459264 (16B aligned)
    int* flag       = (int*)(ws + 524800);        // 1 int        @524800

    hipMemsetAsync(deg, 0, N_ * sizeof(int), stream);
    k_detect<<<1, 256, 0, stream>>>(ei, flag);
    k_count<<<E_ / 256, 256, 0, stream>>>(ei, flag, deg);
    k_scan<<<1, 256, 0, stream>>>(deg, off, cur);
    k_fill<<<E_ / 256, 256, 0, stream>>>(ei, flag, cur, adj);
    k_pack<<<128, 256, 0, stream>>>(wself, wneigh, wpack);
    k_main<<<B_ * (N_ / 64), 256, 0, stream>>>(x, off, adj, wpack, bias, gma, bta, out);
}

// Round 3
// 388.732 us; speedup vs baseline: 1.0139x; 1.0139x over previous
//
#include <hip/hip_runtime.h>
#include <hip/hip_bf16.h>
#include <stdint.h>

#define B_ 16
#define N_ 16384
#define D_ 128
#define E_ 65536

typedef __attribute__((ext_vector_type(8))) __bf16 bf16x8;
typedef __attribute__((ext_vector_type(4))) float f32x4;

__device__ __forceinline__ uint16_t f2bf(float f) {
    union { float f; uint32_t u; } v;
    v.f = f;
    uint32_t u = v.u;
    uint32_t r = (u + 0x7fffu + ((u >> 16) & 1u)) >> 16;
    return (uint16_t)r;
}

// int64-vs-int32 edge_index probe: sample 64 odd words; all-zero <=> int64.
__device__ __forceinline__ bool ei_is64(const int* __restrict__ ei, int t) {
    int w = ei[2 * (t & 63) + 1];
    return __ballot(w != 0) == 0ull;
}

// ---- fused: degree count (blocks 0..255) + weight prepack (blocks 256..383) ----
// wpack B-frag: lane holds B[k = ks*32 + (lane>>4)*8 + j][n = nt*16 + (lane&15)]
// B[k][n] = k<128 ? W_self[n][k] : W_neigh[n][k-128]
__global__ void k_cntpack(const int* __restrict__ ei,
                          const float* __restrict__ wself,
                          const float* __restrict__ wneigh,
                          int* __restrict__ deg,
                          uint16_t* __restrict__ wpack) {
    int t = threadIdx.x;
    int bid = blockIdx.x;
    if (bid < 256) {
        bool is64 = ei_is64(ei, t);
        int e = bid * 256 + t;
        int d = is64 ? ei[2 * (E_ + e)] : ei[E_ + e];
        atomicAdd(&deg[d], 1);
    } else {
        int g = (bid - 256) * 256 + t;  // 0..32767
        int j = g & 7;
        int lane = (g >> 3) & 63;
        int nt = (g >> 9) & 7;
        int ks = g >> 12;
        int k = ks * 32 + (lane >> 4) * 8 + j;
        int n = nt * 16 + (lane & 15);
        float v = (k < 128) ? wself[n * 128 + k] : wneigh[n * 128 + (k - 128)];
        wpack[g] = f2bf(v);
    }
}

// ---- exclusive scan of 16384 degrees, one block, parallel ----
__global__ void k_scan(const int* __restrict__ deg, int* __restrict__ off,
                       int* __restrict__ cur) {
    __shared__ int ps[256];
    int t = threadIdx.x;
    int vals[64];
    const int4* dv = (const int4*)(deg + t * 64);
    int s = 0;
#pragma unroll
    for (int i = 0; i < 16; i++) {
        int4 v = dv[i];
        vals[4 * i + 0] = v.x; vals[4 * i + 1] = v.y;
        vals[4 * i + 2] = v.z; vals[4 * i + 3] = v.w;
        s += v.x + v.y + v.z + v.w;
    }
    ps[t] = s;
    __syncthreads();
#pragma unroll
    for (int st = 1; st < 256; st <<= 1) {
        int add = (t >= st) ? ps[t - st] : 0;
        __syncthreads();
        ps[t] += add;
        __syncthreads();
    }
    int run = ps[t] - s;  // exclusive base
#pragma unroll
    for (int i = 0; i < 64; i++) {
        off[t * 64 + i] = run;
        cur[t * 64 + i] = run;
        run += vals[i];
    }
    if (t == 255) off[N_] = run;
}

__global__ void k_fill(const int* __restrict__ ei, int* __restrict__ cur,
                       int* __restrict__ adj) {
    int t = threadIdx.x;
    bool is64 = ei_is64(ei, t);
    int e = blockIdx.x * 256 + t;
    int s = is64 ? ei[2 * e] : ei[e];
    int d = is64 ? ei[2 * (E_ + e)] : ei[E_ + e];
    int p = atomicAdd(&cur[d], 1);
    adj[p] = s;
}

// ---- neighbor-mean: one 32-lane half-wave per node, coalesced 512B row reads.
// Writes bf16 mean (256 B) into d_out scratch at row*512 + 256.
__global__ __launch_bounds__(256) void k_agg(const float* __restrict__ x,
                                             const int* __restrict__ off,
                                             const int* __restrict__ adj,
                                             unsigned char* __restrict__ scratch) {
    int t = threadIdx.x;
    int g = blockIdx.x & 15;      // graph fastest -> XCD affinity
    int chunk = blockIdx.x >> 4;  // 0..2047
    int hw = t >> 5, l = t & 31;
    int node = chunk * 8 + hw;
    int o0 = off[node], o1 = off[node + 1];
    const float* xg = x + (size_t)g * N_ * D_;
    float ax = 0.f, ay = 0.f, az = 0.f, aw = 0.f;
    int e = o0;
    for (; e + 1 < o1; e += 2) {
        int s0 = adj[e], s1 = adj[e + 1];
        float4 v0 = *(const float4*)(xg + (size_t)s0 * D_ + l * 4);
        float4 v1 = *(const float4*)(xg + (size_t)s1 * D_ + l * 4);
        ax += v0.x + v1.x; ay += v0.y + v1.y;
        az += v0.z + v1.z; aw += v0.w + v1.w;
    }
    if (e < o1) {
        int s0 = adj[e];
        float4 v0 = *(const float4*)(xg + (size_t)s0 * D_ + l * 4);
        ax += v0.x; ay += v0.y; az += v0.z; aw += v0.w;
    }
    float sc = 1.f / fmaxf((float)(o1 - o0), 1.f);
    uint32_t p0 = (uint32_t)f2bf(ax * sc) | ((uint32_t)f2bf(ay * sc) << 16);
    uint32_t p1 = (uint32_t)f2bf(az * sc) | ((uint32_t)f2bf(aw * sc) << 16);
    uint2 pv; pv.x = p0; pv.y = p1;
    *(uint2*)(scratch + ((size_t)g * N_ + node) * 512 + 256 + l * 8) = pv;
}

// ---- streaming MFMA GEMM + bias + LayerNorm + ReLU ----
__global__ __launch_bounds__(256) void k_main(
    const float* __restrict__ x,         // fp32 [16][16384][128]
    const uint16_t* __restrict__ wpack,  // [8][8][64][8] bf16 frags
    const float* __restrict__ bias,
    const float* __restrict__ gamma_,
    const float* __restrict__ beta_,
    float* out) {                        // out rows double as nb scratch (+256B)
    // A-tile (frag order, 32768 B) aliased with C-tile (fp32, 33792 B)
    __shared__ __align__(16) unsigned char smem[33792];
    __shared__ float prm[3][128];
    uint16_t* As = (uint16_t*)smem;
    float* Cs = (float*)smem;

    int t = threadIdx.x;
    int b = blockIdx.x & 15;     // graph fastest -> XCD affinity
    int tile = blockIdx.x >> 4;  // 0..255
    int node0 = tile * 64;

    if (t < 128) {
        prm[0][t] = bias[t];
        prm[1][t] = gamma_[t];
        prm[2][t] = beta_[t];
    }

    int r = t >> 2;   // row in tile 0..63
    int q = t & 3;    // 32-dim quarter 0..3
    int node = node0 + r;
    const size_t xrow_base = ((size_t)b * N_ + node) * D_;
    int mt = r >> 4, m = r & 15;

    // --- stage self rows (k = 0..127), fp32 -> bf16, frag order ---
    {
        const float4* xv = (const float4*)(x + xrow_base);
#pragma unroll
        for (int c = 0; c < 4; c++) {   // 8-element chunks
            float4 a0 = xv[q * 8 + 2 * c + 0];
            float4 a1 = xv[q * 8 + 2 * c + 1];
            float f[8] = {a0.x, a0.y, a0.z, a0.w, a1.x, a1.y, a1.z, a1.w};
            uint32_t pk[4];
#pragma unroll
            for (int p = 0; p < 4; p++)
                pk[p] = (uint32_t)f2bf(f[2 * p]) | ((uint32_t)f2bf(f[2 * p + 1]) << 16);
            int kc = q * 4 + c;  // chunk index 0..15
            int ks = kc >> 2, qd = kc & 3;
            uint4 v = make_uint4(pk[0], pk[1], pk[2], pk[3]);
            *(uint4*)&As[(((ks * 4 + mt) * 64) + qd * 16 + m) * 8] = v;
        }
    }

    // --- stage neighbor-mean rows (k = 128..255) from bf16 scratch ---
    {
        const uint4* nv = (const uint4*)((const unsigned char*)out +
                                         ((size_t)b * N_ + node) * 512 + 256);
#pragma unroll
        for (int c = 0; c < 4; c++) {
            uint4 v = nv[q * 4 + c];
            int kc = 16 + q * 4 + c;  // chunks 16..31
            int ks = kc >> 2, qd = kc & 3;
            *(uint4*)&As[(((ks * 4 + mt) * 64) + qd * 16 + m) * 8] = v;
        }
    }

    __syncthreads();

    // --- MFMA K-loop: each wave owns 2 n-tiles (32 cols), all 64 rows ---
    int wv = t >> 6;
    int lane = t & 63;
    f32x4 accv[4][2];
#pragma unroll
    for (int i = 0; i < 4; i++)
#pragma unroll
        for (int j = 0; j < 2; j++) {
            f32x4 z = {0.f, 0.f, 0.f, 0.f};
            accv[i][j] = z;
        }

    const uint4* wp = (const uint4*)wpack;
#pragma unroll
    for (int ks = 0; ks < 8; ks++) {
        uint4 b0u = wp[(ks * 8 + 2 * wv + 0) * 64 + lane];
        uint4 b1u = wp[(ks * 8 + 2 * wv + 1) * 64 + lane];
        bf16x8 bf0 = __builtin_bit_cast(bf16x8, b0u);
        bf16x8 bf1 = __builtin_bit_cast(bf16x8, b1u);
#pragma unroll
        for (int mtt = 0; mtt < 4; mtt++) {
            bf16x8 a = *(const bf16x8*)&As[((ks * 4 + mtt) * 64 + lane) * 8];
            accv[mtt][0] = __builtin_amdgcn_mfma_f32_16x16x32_bf16(a, bf0, accv[mtt][0], 0, 0, 0);
            accv[mtt][1] = __builtin_amdgcn_mfma_f32_16x16x32_bf16(a, bf1, accv[mtt][1], 0, 0, 0);
        }
    }

    __syncthreads();  // As is dead; reuse as Cs

    // C/D layout: row = (lane>>4)*4 + reg (+mt*16), col = lane&15 (+ntile*16)
    // Cs layout: addr = row*132 + (col>>5)*33 + (col&31)
#pragma unroll
    for (int mtt = 0; mtt < 4; mtt++)
#pragma unroll
        for (int ntl = 0; ntl < 2; ntl++)
#pragma unroll
            for (int rg = 0; rg < 4; rg++) {
                int row = mtt * 16 + (lane >> 4) * 4 + rg;
                int col = (2 * wv + ntl) * 16 + (lane & 15);
                Cs[row * 132 + (col >> 5) * 33 + (col & 31)] = accv[mtt][ntl][rg];
            }

    __syncthreads();

    // --- bias + LayerNorm + ReLU + fp32 store ---
    {
        float s1 = 0.f, s2 = 0.f;
#pragma unroll
        for (int i = 0; i < 32; i++) {
            float v = Cs[r * 132 + q * 33 + i] + prm[0][q * 32 + i];
            s1 += v;
            s2 += v * v;
        }
        s1 += __shfl_xor(s1, 1, 64);
        s2 += __shfl_xor(s2, 1, 64);
        s1 += __shfl_xor(s1, 2, 64);
        s2 += __shfl_xor(s2, 2, 64);
        float mu = s1 * (1.f / 128.f);
        float var = s2 * (1.f / 128.f) - mu * mu;
        float rstd = rsqrtf(var + 1e-5f);

        float* orow = out + xrow_base;
#pragma unroll
        for (int c = 0; c < 8; c++) {   // 4-float groups
            float4 o;
            float tmp[4];
#pragma unroll
            for (int j = 0; j < 4; j++) {
                int i0 = c * 4 + j;
                int d0 = q * 32 + i0;
                float v = Cs[r * 132 + q * 33 + i0] + prm[0][d0];
                tmp[j] = fmaxf((v - mu) * rstd * prm[1][d0] + prm[2][d0], 0.f);
            }
            o.x = tmp[0]; o.y = tmp[1]; o.z = tmp[2]; o.w = tmp[3];
            *(float4*)&orow[q * 32 + c * 4] = o;
        }
    }
}

extern "C" void kernel_launch(void* const* d_in, const int* in_sizes, int n_in,
                              void* d_out, int out_size, void* d_ws, size_t ws_size,
                              hipStream_t stream) {
    (void)in_sizes; (void)n_in; (void)out_size; (void)ws_size;
    const float* x      = (const float*)d_in[0];
    const int*   ei     = (const int*)d_in[1];
    // d_in[2] = batch_size (16), compile-time constant here
    const float* wself  = (const float*)d_in[3];
    const float* wneigh = (const float*)d_in[4];
    const float* bias   = (const float*)d_in[5];
    const float* gma    = (const float*)d_in[6];
    const float* bta    = (const float*)d_in[7];
    float* out = (float*)d_out;

    char* ws = (char*)d_ws;
    int* deg        = (int*)(ws);                 // 16384 ints   @0
    int* off        = (int*)(ws + 65536);         // 16385 ints   @65536
    int* cur        = (int*)(ws + 131584);        // 16384 ints   @131584
    int* adj        = (int*)(ws + 197120);        // 65536 ints   @197120
    uint16_t* wpack = (uint16_t*)(ws + 459264);   // 32768 bf16   @459264

    hipMemsetAsync(deg, 0, N_ * sizeof(int), stream);
    k_cntpack<<<384, 256, 0, stream>>>(ei, wself, wneigh, deg, wpack);
    k_scan<<<1, 256, 0, stream>>>(deg, off, cur);
    k_fill<<<E_ / 256, 256, 0, stream>>>(ei, cur, adj);
    k_agg<<<B_ * N_ / 8, 256, 0, stream>>>(x, off, adj, (unsigned char*)out);
    k_main<<<B_ * (N_ / 64), 256, 0, stream>>>(x, wpack, bias, gma, bta, out);
}